// Round 1
// baseline (110.165 us; speedup 1.0000x reference)
//
#include <hip/hip_runtime.h>
#include <stdint.h>

#define KN 9
#define HH 64
#define WW 64
#define CC 128
#define FF 128
#define TM 64      // pixels per block (one full image row)
#define NT 512     // threads per block (8 waves)
#define LDK 136    // padded LDS K-stride (bf16 elements); 272 B row = 16B-aligned

typedef __bf16 bf16x8 __attribute__((ext_vector_type(8)));
typedef float f32x4 __attribute__((ext_vector_type(4)));
typedef unsigned short us8 __attribute__((ext_vector_type(8)));

// Reference tap layout (verified R3): stack(meshgrid(ij)).reshape(-1,2) pairs
// the C-order flatten of (2,3,3) across the I/J boundary.
__constant__ float c_init_i[KN] = {0.f,0.f,1.f,2.f,2.f,1.f,0.f,2.f,1.f};
__constant__ float c_init_j[KN] = {0.f,1.f,1.f,2.f,0.f,2.f,1.f,0.f,2.f};

static __device__ inline unsigned short f2bf(float f) {
    union { float f; unsigned u; } v; v.f = f;
    unsigned r = v.u + 0x7fffu + ((v.u >> 16) & 1u);  // RNE
    return (unsigned short)(r >> 16);
}

// Transpose + quantize W: (KN, C, F) fp32 -> Wt bf16 in B-FRAGMENT layout:
//   idx = n*16384 + (c>>5)*4096 + f*32 + (c&31)
// so a wave's MFMA B-fragment load (16 f-rows x 64B) is one contiguous 1KB read.
__global__ void wt_kernel(const float* __restrict__ Wk, unsigned short* __restrict__ Wt) {
    __shared__ unsigned short t[32][33];
    const int tid = threadIdx.x;
    const int n  = blockIdx.x >> 4;
    const int tf = blockIdx.x & 3;        // f-tile
    const int tc = (blockIdx.x >> 2) & 3; // c-tile (== ks, since 32-wide)
    const int g  = tid >> 5;              // 0..7
    const int l  = tid & 31;
#pragma unroll
    for (int r = 0; r < 4; ++r) {
        int cl = g * 4 + r;
        t[cl][l] = f2bf(Wk[(n << 14) + ((tc * 32 + cl) << 7) + (tf * 32 + l)]);
    }
    __syncthreads();
#pragma unroll
    for (int r = 0; r < 4; ++r) {
        int fl = g * 4 + r;
        // idx = n*16384 + tc*4096 + (tf*32+fl)*32 + l  (consecutive l -> coalesced)
        Wt[(n << 14) + (tc << 12) + ((tf * 32 + fl) << 5) + l] = t[l][fl];
    }
}

__launch_bounds__(NT, 4)   // cap at 128 VGPR: 2 blocks/CU needs 4 waves/SIMD
__global__ void deform_kernel(const float* __restrict__ xin,
                              const float* __restrict__ off,
                              const unsigned short* __restrict__ Wt,
                              const float* __restrict__ bias,
                              float* __restrict__ out) {
    __shared__ unsigned short As[TM][LDK];   // deform tile, bf16, M x K: 17408 B
    __shared__ int   cB[TM][KN][4];          // 4 corner element-offsets: 9216 B
    __shared__ float cF[TM][KN][2];          // (fy, fx): 4608 B
    // total 31232 B -> 2 blocks/CU (Bt LDS eliminated: B-frags come from L2)

    const int tid = threadIdx.x;
    // XCD swizzle (verified R5: FETCH 196->10.5 MB): image b -> XCD b.
    const int bb   = blockIdx.x & 7;
    const int hh   = blockIdx.x >> 3;
    const int pix0 = (bb << 12) + (hh << 6);

    // ---- phase 0: precompute corner offsets + fractions once per (p, n) ----
    for (int t = tid; t < TM * KN; t += NT) {
        int p = t & (TM - 1);
        int n = t >> 6;
        const float* op = off + (size_t)(pix0 + p) * (2 * KN) + 2 * n;
        float y = (float)(hh - 1) + c_init_i[n] + op[0];
        float x = (float)(p - 1) + c_init_j[n] + op[1];
        y = fminf(fmaxf(y, 0.f), 63.f);
        x = fminf(fmaxf(x, 0.f), 63.f);
        float y0f = floorf(y), x0f = floorf(x);
        int y0 = (int)y0f, x0 = (int)x0f;
        int y1 = (int)ceilf(y), x1 = (int)ceilf(x);
        cB[p][n][0] = ((y0 << 6) + x0) << 7;   // lt
        cB[p][n][1] = ((y1 << 6) + x0) << 7;   // rt (y1, x0) per TF coords_rt
        cB[p][n][2] = ((y0 << 6) + x1) << 7;   // lb (y0, x1) per TF coords_lb
        cB[p][n][3] = ((y1 << 6) + x1) << 7;   // rb
        cF[p][n][0] = y - y0f;
        cF[p][n][1] = x - x0f;
    }

    const int wave = tid >> 6;
    const int lane = tid & 63;
    const int quad = lane >> 4;
    const int col  = lane & 15;
    const int mtile = (wave & 1) * 32;   // 2 M-supertiles of 32 pixels
    const int ntile = (wave >> 1) * 32;  // 4 N-supertiles of 32 filters

    f32x4 acc[2][2];
#pragma unroll
    for (int a = 0; a < 2; ++a)
#pragma unroll
        for (int b = 0; b < 2; ++b) acc[a][b] = (f32x4){0.f, 0.f, 0.f, 0.f};

    const float* bbase = xin + ((size_t)bb << 19);
    // B-fragment base for this wave: f = ntile+col (+16), c-chunk = quad*8
    const unsigned short* wb0 = Wt + ((ntile + col) << 5) + (quad << 3);

    // 2 gather items per tap, 8 channels each: i in [0,1024), p = i>>4, cg = (i&15)*8
    const int ip0 = tid >> 4;
    const int ip1 = ip0 + 32;
    const int icg = (tid & 15) * 8;

    // issue the 8 corner-half loads for one gather item (no wait)
    auto issue = [&](int n, int p, float4* pf) {
        int4 cb = *(const int4*)&cB[p][n][0];    // broadcast b128 (4 addrs/wave)
        const float* c0 = bbase + cb.x + icg;
        const float* c1 = bbase + cb.y + icg;
        const float* c2 = bbase + cb.z + icg;
        const float* c3 = bbase + cb.w + icg;
        pf[0] = *(const float4*)c0; pf[1] = *(const float4*)(c0 + 4);
        pf[2] = *(const float4*)c1; pf[3] = *(const float4*)(c1 + 4);
        pf[4] = *(const float4*)c2; pf[5] = *(const float4*)(c2 + 4);
        pf[6] = *(const float4*)c3; pf[7] = *(const float4*)(c3 + 4);
    };
    // interp prefetched corners (8 channels) and write As
    auto consume = [&](int n, int p, const float4* pf) {
        float fy = cF[p][n][0], fx = cF[p][n][1];  // broadcast b64
        us8 pk;
#pragma unroll
        for (int j = 0; j < 8; ++j) {
            float v0 = pf[0 + (j >> 2)][j & 3];
            float v1 = pf[2 + (j >> 2)][j & 3];
            float v2 = pf[4 + (j >> 2)][j & 3];
            float v3 = pf[6 + (j >> 2)][j & 3];
            float vt = v0 + (v1 - v0) * fy;
            float vb = v2 + (v3 - v2) * fy;
            float r  = vt + (vb - vt) * fx;
            pk[j] = __builtin_bit_cast(unsigned short, (__bf16)r);  // v_cvt_pk_bf16_f32
        }
        *(us8*)&As[p][icg] = pk;   // one b128 write
    };

    __syncthreads();   // coords ready

    float4 pf0[8], pf1[8];
    us8 bfr[8];
    issue(0, ip0, pf0);   // prologue: item 0 of tap 0

    for (int n = 0; n < KN; ++n) {
        // B-fragments for this tap, direct from L2 (Wt is 294KB, L2-resident).
        // Issued first; the whole gather+interp phase covers their latency.
        const unsigned short* wn = wb0 + (n << 14);
#pragma unroll
        for (int ks = 0; ks < 4; ++ks) {
            bfr[ks * 2]     = *(const us8*)(wn + (ks << 12));
            bfr[ks * 2 + 1] = *(const us8*)(wn + (ks << 12) + (16 << 5));
        }
        issue(n, ip1, pf1);
        consume(n, ip0, pf0);
        consume(n, ip1, pf1);
        __syncthreads();   // As ready

        // prefetch NEXT tap's item 0 before the MFMA phase: flies under MFMA
        if (n + 1 < KN) issue(n + 1, ip0, pf0);

        // ---- MFMA: 32x32 wave tile, 4 K-steps of 32; B from registers ----
#pragma unroll
        for (int ks = 0; ks < 4; ++ks) {
            bf16x8 a0 = __builtin_bit_cast(bf16x8, *(const us8*)(&As[mtile + col][ks * 32 + quad * 8]));
            bf16x8 a1 = __builtin_bit_cast(bf16x8, *(const us8*)(&As[mtile + 16 + col][ks * 32 + quad * 8]));
            bf16x8 b0 = __builtin_bit_cast(bf16x8, bfr[ks * 2]);
            bf16x8 b1 = __builtin_bit_cast(bf16x8, bfr[ks * 2 + 1]);
            acc[0][0] = __builtin_amdgcn_mfma_f32_16x16x32_bf16(a0, b0, acc[0][0], 0, 0, 0);
            acc[0][1] = __builtin_amdgcn_mfma_f32_16x16x32_bf16(a0, b1, acc[0][1], 0, 0, 0);
            acc[1][0] = __builtin_amdgcn_mfma_f32_16x16x32_bf16(a1, b0, acc[1][0], 0, 0, 0);
            acc[1][1] = __builtin_amdgcn_mfma_f32_16x16x32_bf16(a1, b1, acc[1][1], 0, 0, 0);
        }
        __syncthreads();   // protect As overwrite next tap
    }

    // ---- epilogue: C/D layout col=lane&15, row=quad*4+reg (HW-verified) ----
#pragma unroll
    for (int b = 0; b < 2; ++b) {
        int f = ntile + b * 16 + col;
        float bv = bias[f];
#pragma unroll
        for (int a = 0; a < 2; ++a) {
#pragma unroll
            for (int r = 0; r < 4; ++r) {
                int pr = pix0 + mtile + a * 16 + quad * 4 + r;
                out[(size_t)pr * FF + f] = acc[a][b][r] + bv;
            }
        }
    }
}

extern "C" void kernel_launch(void* const* d_in, const int* in_sizes, int n_in,
                              void* d_out, int out_size, void* d_ws, size_t ws_size,
                              hipStream_t stream) {
    const float* x    = (const float*)d_in[0];
    const float* off  = (const float*)d_in[1];
    const float* Wk   = (const float*)d_in[2];
    const float* bias = (const float*)d_in[3];
    float* out = (float*)d_out;
    unsigned short* Wt = (unsigned short*)d_ws;  // 9*128*128 bf16 = 294912 B

    wt_kernel<<<KN * 16, 256, 0, stream>>>(Wk, Wt);
    deform_kernel<<<(8 * HH * WW) / TM, NT, 0, stream>>>(x, off, Wt, bias, out);
}